// Round 9
// baseline (4527.097 us; speedup 1.0000x reference)
//
#include <hip/hip_runtime.h>

typedef unsigned short u16;
typedef unsigned int u32;
typedef short bf16x8 __attribute__((ext_vector_type(8)));
typedef float f32x4 __attribute__((ext_vector_type(4)));

#define S_LEN 500
#define EDIM 128

// LDS u16-index map: 4 swizzled weight matrices + per-tile k/qq/sd buffers
#define W_LDS(m) ((m) * 16384)                 // m: 0=W1, 1=W2, 2=W3, 3=W6
#define KBUF(tt) (65536 + (tt) * 2176)
#define QQBUF(tt) (65536 + 4352 + (tt) * 2176)
#define SDBUF(tt) (65536 + 8704 + (tt) * 2176)
#define LDS_BYTES 157184

__device__ __forceinline__ float bf2f(u16 u) { return __uint_as_float(((u32)u) << 16); }
__device__ __forceinline__ u16 f2bf(float f) {
    u32 x = __float_as_uint(f);
    x += 0x7FFFu + ((x >> 16) & 1u);   // RNE
    return (u16)(x >> 16);
}
__device__ __forceinline__ float lo16(u32 v) { return __uint_as_float(v << 16); }
__device__ __forceinline__ float hi16(u32 v) { return __uint_as_float(v & 0xFFFF0000u); }
__device__ __forceinline__ float fexp(float x) { return __builtin_amdgcn_exp2f(x * 1.44269504089f); }
__device__ __forceinline__ float frcp(float x) { return __builtin_amdgcn_rcpf(x); }
__device__ __forceinline__ float sigm(float x) { return frcp(1.0f + fexp(-x)); }
__device__ __forceinline__ float tanh_(float x) { return 1.0f - 2.0f * frcp(1.0f + fexp(2.0f * x)); }

// HW barrier WITHOUT vmcnt drain: only LDS handoffs cross it; global prefetch
// stays in flight (R8's win mechanism, minus the atomic-poll latency).
#define WGSYNC() __asm__ volatile("s_waitcnt lgkmcnt(0)\n\ts_barrier" ::: "memory")

__device__ __forceinline__ bool detect_bf16(const void* q) {
    const u16* w = (const u16*)q;
    int plaus = 0;
#pragma unroll 1
    for (int i = 0; i < 64; ++i) {
        const u16 v = w[2 * i];
        const int e = (v >> 7) & 0xFF;
        plaus += (v == 0 || (e >= 100 && e <= 130)) ? 1 : 0;
    }
    return plaus >= 48;
}
__device__ __forceinline__ float ldF(const void* p, int i, bool bf) {
    return bf ? bf2f(((const u16*)p)[i]) : ((const float*)p)[i];
}
template <bool BF>
__device__ __forceinline__ bf16x8 ldfragT(const void* p, int i) {
    if (BF) return *(const bf16x8*)((const u16*)p + i);
    const float* f = (const float*)p + i;
    bf16x8 r;
#pragma unroll
    for (int e = 0; e < 8; ++e) r[e] = (short)f2bf(f[e]);
    return r;
}

__global__ void dimkt_sentinel(u16* __restrict__ out, u16 val) {
    out[blockIdx.x * 256 + threadIdx.x] = val;
}

// ---------------------------------------------------------------------------
// K0: gather-table precompute. First 4 outputs bf16-packed (register relief in
// the scan), c4t/c5t stay fp32.
// ---------------------------------------------------------------------------
__global__ void dimkt_tabs(const void* __restrict__ q_emb,
                           const void* __restrict__ c_tab, const void* __restrict__ sd_tab,
                           const void* __restrict__ qd_tab, const void* __restrict__ a_tab,
                           const void* __restrict__ W1, const void* __restrict__ W4,
                           const void* __restrict__ W5, const void* __restrict__ W6,
                           const void* __restrict__ b4, const void* __restrict__ b5,
                           const void* __restrict__ b6,
                           u16* __restrict__ cW1pu, u16* __restrict__ sdQu,
                           u16* __restrict__ qdQu, u16* __restrict__ aW6pu,
                           float* __restrict__ c4t, float* __restrict__ c5t) {
    const bool bf = detect_bf16(q_emb);
    __shared__ float src[128];
    const int r = blockIdx.x, n = threadIdx.x;
    const int w = n >> 5, jj = (n >> 4) & 1, l = n & 15;
    const void* srcp; const void* W; const void* bias = nullptr;
    int soff, koff, ld, oidx; u16* outU = nullptr; float* outF = nullptr; bool mask;
    if (r < 1001)      { srcp = c_tab;  soff = r * 128;               W = W1; koff = 128; ld = 512; outU = cW1pu; oidx = r * 128 + w * 32 + l * 2 + jj;        mask = (r == 0); }
    else if (r < 1103) { int rr = r - 1001; srcp = sd_tab; soff = rr * 128; W = W1; koff = 256; ld = 512; outU = sdQu;  oidx = rr * 256 + w * 64 + l * 4 + jj;     mask = (rr == 0); }
    else if (r < 1205) { int rr = r - 1103; srcp = qd_tab; soff = rr * 128; W = W1; koff = 384; ld = 512; outU = qdQu;  oidx = rr * 256 + w * 64 + l * 4 + jj;     mask = (rr == 0); }
    else if (r < 1307) { int rr = r - 1205; srcp = sd_tab; soff = rr * 128; W = W6; koff = 256; ld = 512; outU = sdQu;  oidx = rr * 256 + w * 64 + l * 4 + 2 + jj; mask = (rr == 0); }
    else if (r < 1409) { int rr = r - 1307; srcp = qd_tab; soff = rr * 128; W = W6; koff = 384; ld = 512; outU = qdQu;  oidx = rr * 256 + w * 64 + l * 4 + 2 + jj; mask = (rr == 0); }
    else if (r < 1411) { int rr = r - 1409; srcp = a_tab;  soff = rr * 128; W = W6; koff = 128; ld = 512; outU = aW6pu; oidx = rr * 128 + w * 32 + l * 2 + jj;     bias = b6; mask = false; }
    else if (r < 1413) { int rr = r - 1411; srcp = a_tab;  soff = rr * 128; W = W4; koff = 128; ld = 256; outF = c4t;  oidx = rr * 128 + n;                       bias = b4; mask = false; }
    else               { int rr = r - 1413; srcp = a_tab;  soff = rr * 128; W = W5; koff = 128; ld = 256; outF = c5t;  oidx = rr * 128 + n;                       bias = b5; mask = false; }
    src[n] = ldF(srcp, soff + n, bf);
    __syncthreads();
    float acc = 0.f;
    if (!mask) {
        for (int k = 0; k < 128; ++k) acc += src[k] * ldF(W, n * ld + koff + k, bf);
        if (bias) acc += ldF(bias, n, bf);
    }
    if (outU) outU[oidx] = f2bf(acc);
    else      outF[oidx] = acc;
}

// ---------------------------------------------------------------------------
// K2: fused 500-step scan, 8 WGs x 256 thr; each wave processes TWO 16-row
// tiles (rows b0, b0+16) for its 32 cols -> second tile's compute absorbs the
// first's stalls (1 wave/SIMD, no TLP otherwise). W1/W2/W3/W6 staged in LDS
// (xor-swizzled, conflict-free b128), W4/W5 register-resident. Sync = raw
// s_barrier + lgkmcnt only (no vmcnt drain).
// ---------------------------------------------------------------------------
template <bool BF>
__global__ __launch_bounds__(256, 1) void dimkt_scan(
    const void* __restrict__ q_emb,
    const int* __restrict__ cI, const int* __restrict__ sI,
    const int* __restrict__ qI, const int* __restrict__ aI,
    const void* __restrict__ W1, const void* __restrict__ b1,
    const void* __restrict__ W2, const void* __restrict__ b2,
    const void* __restrict__ W3, const void* __restrict__ b3,
    const void* __restrict__ W4, const void* __restrict__ W5,
    const void* __restrict__ W6, const void* __restrict__ knowledge,
    const u16* __restrict__ cW1pu, const u16* __restrict__ sdQu,
    const u16* __restrict__ qdQu, const u16* __restrict__ aW6pu,
    const float* __restrict__ c4t, const float* __restrict__ c5t,
    void* __restrict__ outv) {
    if (detect_bf16(q_emb) != BF) return;
    extern __shared__ u16 lds[];

    const int tid = threadIdx.x;
    const int wv = tid >> 6, lane = tid & 63;
    const int quad = lane >> 4, l15 = lane & 15;
    const int b0[2] = {(int)blockIdx.x * 32, (int)blockIdx.x * 32 + 16};

    // ---- stage W1,W2,W3,W6[:, :128] into LDS, xor-swizzled ----
    {
        const int col = tid & 127, half = tid >> 7, sw = col & 15;
        const void* srcs[4] = {W1, W2, W3, W6};
        const int lda[4] = {512, 128, 128, 512};
#pragma unroll
        for (int m = 0; m < 4; ++m) {
            u16* dst = lds + W_LDS(m) + col * 128;
#pragma unroll
            for (int kc = half * 8; kc < half * 8 + 8; ++kc) {
                if (BF) {
                    *(uint4*)&dst[(kc ^ sw) * 8] =
                        *(const uint4*)((const u16*)srcs[m] + col * lda[m] + kc * 8);
                } else {
                    const float* s = (const float*)srcs[m] + col * lda[m] + kc * 8;
                    u16 tmp[8];
#pragma unroll
                    for (int e = 0; e < 8; ++e) tmp[e] = f2bf(s[e]);
                    *(uint4*)&dst[(kc ^ sw) * 8] = *(uint4*)tmp;
                }
            }
        }
    }

    // ---- persistent: W4/W5 fragments + scalars ----
    bf16x8 fW4[2][4], fW5[2][4];
    float b1v[2], b2v[2], b3v[2], c4_0[2], c4_1[2], c5_0[2], c5_1[2];
    int col_[2];
#pragma unroll
    for (int j = 0; j < 2; ++j) {
        const int col = wv * 32 + j * 16 + l15;
        col_[j] = col;
#pragma unroll
        for (int ks = 0; ks < 4; ++ks) {
            const int ko = ks * 32 + quad * 8;
            fW4[j][ks] = ldfragT<BF>(W4, col * 256 + ko);
            fW5[j][ks] = ldfragT<BF>(W5, col * 256 + ko);
        }
        b1v[j] = ldF(b1, col, BF);
        b2v[j] = ldF(b2, col, BF);
        b3v[j] = ldF(b3, col, BF);
        c4_0[j] = c4t[col]; c4_1[j] = c4t[128 + col];
        c5_0[j] = c5t[col]; c5_1[j] = c5t[128 + col];
    }
    __syncthreads();   // W staging visible

    // LDS fragment readers
    auto ldw = [&](int m, int j, int ks) -> bf16x8 {
        const int c = col_[j];
        return *(const bf16x8*)&lds[W_LDS(m) + c * 128 + ((((ks << 2) | quad) ^ (c & 15)) << 3)];
    };
    auto rdA = [&](int base, int ks) -> bf16x8 {
        return *(const bf16x8*)&lds[base + l15 * 136 + ks * 32 + quad * 8];
    };

    // ---- carried state ----
    float kold[2][2][4], z6c[2][2][4];
    int ac[2][4];

    // ---- t=0 init ----
#pragma unroll
    for (int tt = 0; tt < 2; ++tt) {
        float inpA0[2][4];
#pragma unroll
        for (int i = 0; i < 4; ++i) {
            const int off = (b0[tt] + quad * 4 + i) * S_LEN;
            const int cx = cI[off], sx = sI[off], qx = qI[off], ax = aI[off];
            ac[tt][i] = ax;
            const u32 cgu = *(const u32*)&cW1pu[cx * 128 + wv * 32 + l15 * 2];
            const uint2 sgu = *(const uint2*)&sdQu[sx * 256 + wv * 64 + l15 * 4];
            const uint2 qgu = *(const uint2*)&qdQu[qx * 256 + wv * 64 + l15 * 4];
            const u32 agu = *(const u32*)&aW6pu[ax * 128 + wv * 32 + l15 * 2];
            inpA0[0][i] = lo16(cgu) + lo16(sgu.x) + lo16(qgu.x);
            inpA0[1][i] = hi16(cgu) + hi16(sgu.x) + hi16(qgu.x);
            z6c[tt][0][i] = lo16(agu) + lo16(sgu.y) + lo16(qgu.y);
            z6c[tt][1][i] = hi16(agu) + hi16(sgu.y) + hi16(qgu.y);
        }
        bf16x8 ae0[4];
#pragma unroll
        for (int ks = 0; ks < 4; ++ks)
            ae0[ks] = ldfragT<BF>(q_emb, ((b0[tt] + l15) * S_LEN) * EDIM + ks * 32 + quad * 8);
        f32x4 Y1[2];
#pragma unroll
        for (int j = 0; j < 2; ++j) {
            Y1[j] = (f32x4){b1v[j] + inpA0[j][0], b1v[j] + inpA0[j][1],
                            b1v[j] + inpA0[j][2], b1v[j] + inpA0[j][3]};
#pragma unroll
            for (int ks = 0; ks < 4; ++ks)
                Y1[j] = __builtin_amdgcn_mfma_f32_16x16x32_bf16(ae0[ks], ldw(0, j, ks), Y1[j], 0, 0, 0);
        }
#pragma unroll
        for (int j = 0; j < 2; ++j) {
            const float k0 = ldF(knowledge, col_[j], BF);
#pragma unroll
            for (int i = 0; i < 4; ++i) {
                kold[tt][j][i] = k0;
                const int widx = (quad * 4 + i) * 136 + col_[j];
                lds[KBUF(tt) + widx] = f2bf(k0);
                lds[QQBUF(tt) + widx] = f2bf(k0 - Y1[j][i]);
            }
        }
    }
    WGSYNC();

    // ---- main loop ----
#pragma unroll 1
    for (int t = 0; t < S_LEN; ++t) {
        const int tn = (t + 1 < S_LEN) ? t + 1 : S_LEN - 1;
        // idx(t+1) both tiles; ae(t+1) both tiles
        int cN[2][4], sN[2][4], qN[2][4], aN[2][4];
        bf16x8 ae[2][4];
#pragma unroll
        for (int tt = 0; tt < 2; ++tt) {
#pragma unroll
            for (int i = 0; i < 4; ++i) {
                const int off = (b0[tt] + quad * 4 + i) * S_LEN + tn;
                cN[tt][i] = cI[off]; sN[tt][i] = sI[off];
                qN[tt][i] = qI[off]; aN[tt][i] = aI[off];
            }
#pragma unroll
            for (int ks = 0; ks < 4; ++ks)
                ae[tt][ks] = ldfragT<BF>(q_emb, ((b0[tt] + l15) * S_LEN + tn) * EDIM + ks * 32 + quad * 8);
        }
        // tile0 gathers issued early
        u32 cg0[4], ag0[4]; uint2 sg0[4], qg0[4];
#pragma unroll
        for (int i = 0; i < 4; ++i) {
            cg0[i] = *(const u32*)&cW1pu[cN[0][i] * 128 + wv * 32 + l15 * 2];
            sg0[i] = *(const uint2*)&sdQu[sN[0][i] * 256 + wv * 64 + l15 * 4];
            qg0[i] = *(const uint2*)&qdQu[qN[0][i] * 256 + wv * 64 + l15 * 4];
            ag0[i] = *(const u32*)&aW6pu[aN[0][i] * 128 + wv * 32 + l15 * 2];
        }

        // ---- phase B ----
        bf16x8 aq[2][4];
#pragma unroll
        for (int tt = 0; tt < 2; ++tt)
#pragma unroll
            for (int ks = 0; ks < 4; ++ks) aq[tt][ks] = rdA(QQBUF(tt), ks);
        f32x4 Y2[2][2], Y3[2][2];
#pragma unroll
        for (int tt = 0; tt < 2; ++tt)
#pragma unroll
            for (int j = 0; j < 2; ++j) {
                Y2[tt][j] = (f32x4){b2v[j], b2v[j], b2v[j], b2v[j]};
                Y3[tt][j] = (f32x4){b3v[j], b3v[j], b3v[j], b3v[j]};
            }
#pragma unroll
        for (int j = 0; j < 2; ++j)
#pragma unroll
            for (int ks = 0; ks < 4; ++ks) {
                const bf16x8 w2 = ldw(1, j, ks);
                Y2[0][j] = __builtin_amdgcn_mfma_f32_16x16x32_bf16(aq[0][ks], w2, Y2[0][j], 0, 0, 0);
                Y2[1][j] = __builtin_amdgcn_mfma_f32_16x16x32_bf16(aq[1][ks], w2, Y2[1][j], 0, 0, 0);
            }
#pragma unroll
        for (int j = 0; j < 2; ++j)
#pragma unroll
            for (int ks = 0; ks < 4; ++ks) {
                const bf16x8 w3 = ldw(2, j, ks);
                Y3[0][j] = __builtin_amdgcn_mfma_f32_16x16x32_bf16(aq[0][ks], w3, Y3[0][j], 0, 0, 0);
                Y3[1][j] = __builtin_amdgcn_mfma_f32_16x16x32_bf16(aq[1][ks], w3, Y3[1][j], 0, 0, 0);
            }
        // tile0 sums; tile1 gathers issued
        float inpA[2][2][4], z6n[2][2][4];
#pragma unroll
        for (int i = 0; i < 4; ++i) {
            inpA[0][0][i] = lo16(cg0[i]) + lo16(sg0[i].x) + lo16(qg0[i].x);
            inpA[0][1][i] = hi16(cg0[i]) + hi16(sg0[i].x) + hi16(qg0[i].x);
            z6n[0][0][i] = lo16(ag0[i]) + lo16(sg0[i].y) + lo16(qg0[i].y);
            z6n[0][1][i] = hi16(ag0[i]) + hi16(sg0[i].y) + hi16(qg0[i].y);
        }
        u32 cg1[4], ag1[4]; uint2 sg1[4], qg1[4];
#pragma unroll
        for (int i = 0; i < 4; ++i) {
            cg1[i] = *(const u32*)&cW1pu[cN[1][i] * 128 + wv * 32 + l15 * 2];
            sg1[i] = *(const uint2*)&sdQu[sN[1][i] * 256 + wv * 64 + l15 * 4];
            qg1[i] = *(const uint2*)&qdQu[qN[1][i] * 256 + wv * 64 + l15 * 4];
            ag1[i] = *(const u32*)&aW6pu[aN[1][i] * 128 + wv * 32 + l15 * 2];
        }
        // Y6 on k; Y1n on ae(t+1)
        bf16x8 ak[2][4];
#pragma unroll
        for (int tt = 0; tt < 2; ++tt)
#pragma unroll
            for (int ks = 0; ks < 4; ++ks) ak[tt][ks] = rdA(KBUF(tt), ks);
        f32x4 Y6[2][2], Y1n[2][2];
#pragma unroll
        for (int tt = 0; tt < 2; ++tt)
#pragma unroll
            for (int j = 0; j < 2; ++j) {
                Y6[tt][j] = (f32x4){z6c[tt][j][0], z6c[tt][j][1], z6c[tt][j][2], z6c[tt][j][3]};
                Y1n[tt][j] = (f32x4){b1v[j], b1v[j], b1v[j], b1v[j]};
            }
#pragma unroll
        for (int j = 0; j < 2; ++j)
#pragma unroll
            for (int ks = 0; ks < 4; ++ks) {
                const bf16x8 w6 = ldw(3, j, ks);
                Y6[0][j] = __builtin_amdgcn_mfma_f32_16x16x32_bf16(ak[0][ks], w6, Y6[0][j], 0, 0, 0);
                Y6[1][j] = __builtin_amdgcn_mfma_f32_16x16x32_bf16(ak[1][ks], w6, Y6[1][j], 0, 0, 0);
            }
#pragma unroll
        for (int j = 0; j < 2; ++j)
#pragma unroll
            for (int ks = 0; ks < 4; ++ks) {
                const bf16x8 w1 = ldw(0, j, ks);
                Y1n[0][j] = __builtin_amdgcn_mfma_f32_16x16x32_bf16(ae[0][ks], w1, Y1n[0][j], 0, 0, 0);
                Y1n[1][j] = __builtin_amdgcn_mfma_f32_16x16x32_bf16(ae[1][ks], w1, Y1n[1][j], 0, 0, 0);
            }
        // tile1 sums
#pragma unroll
        for (int i = 0; i < 4; ++i) {
            inpA[1][0][i] = lo16(cg1[i]) + lo16(sg1[i].x) + lo16(qg1[i].x);
            inpA[1][1][i] = hi16(cg1[i]) + hi16(sg1[i].x) + hi16(qg1[i].x);
            z6n[1][0][i] = lo16(ag1[i]) + lo16(sg1[i].y) + lo16(qg1[i].y);
            z6n[1][1][i] = hi16(ag1[i]) + hi16(sg1[i].y) + hi16(qg1[i].y);
        }
        // trans + sdbuf write + g
        float g[2][2][4];
#pragma unroll
        for (int tt = 0; tt < 2; ++tt)
#pragma unroll
            for (int j = 0; j < 2; ++j)
#pragma unroll
                for (int i = 0; i < 4; ++i) {
                    const float sdv = sigm(Y2[tt][j][i]) * tanh_(Y3[tt][j][i]);
                    lds[SDBUF(tt) + (quad * 4 + i) * 136 + col_[j]] = f2bf(sdv);
                    g[tt][j][i] = sigm(Y6[tt][j][i]);
                }
        WGSYNC();

        // ---- phase C ----
        bf16x8 as_[2][4];
#pragma unroll
        for (int tt = 0; tt < 2; ++tt)
#pragma unroll
            for (int ks = 0; ks < 4; ++ks) as_[tt][ks] = rdA(SDBUF(tt), ks);
        f32x4 Y4[2][2], Y5[2][2];
#pragma unroll
        for (int tt = 0; tt < 2; ++tt)
#pragma unroll
            for (int j = 0; j < 2; ++j) {
                Y4[tt][j] = (f32x4){ac[tt][0] ? c4_1[j] : c4_0[j], ac[tt][1] ? c4_1[j] : c4_0[j],
                                    ac[tt][2] ? c4_1[j] : c4_0[j], ac[tt][3] ? c4_1[j] : c4_0[j]};
                Y5[tt][j] = (f32x4){ac[tt][0] ? c5_1[j] : c5_0[j], ac[tt][1] ? c5_1[j] : c5_0[j],
                                    ac[tt][2] ? c5_1[j] : c5_0[j], ac[tt][3] ? c5_1[j] : c5_0[j]};
#pragma unroll
                for (int ks = 0; ks < 4; ++ks) {
                    Y4[tt][j] = __builtin_amdgcn_mfma_f32_16x16x32_bf16(as_[tt][ks], fW4[j][ks], Y4[tt][j], 0, 0, 0);
                    Y5[tt][j] = __builtin_amdgcn_mfma_f32_16x16x32_bf16(as_[tt][ks], fW5[j][ks], Y5[tt][j], 0, 0, 0);
                }
            }
#pragma unroll
        for (int tt = 0; tt < 2; ++tt)
#pragma unroll
            for (int j = 0; j < 2; ++j)
#pragma unroll
                for (int i = 0; i < 4; ++i) {
                    const float pk = sigm(Y4[tt][j][i]) * tanh_(Y5[tt][j][i]);
                    const float kn = g[tt][j][i] * kold[tt][j][i] + (1.0f - g[tt][j][i]) * pk;
                    kold[tt][j][i] = kn;
                    const int widx = (quad * 4 + i) * 136 + col_[j];
                    lds[KBUF(tt) + widx] = f2bf(kn);
                    lds[QQBUF(tt) + widx] = f2bf(kn - (Y1n[tt][j][i] + inpA[tt][j][i]));
                }
        // rotate carried state
#pragma unroll
        for (int tt = 0; tt < 2; ++tt)
#pragma unroll
            for (int i = 0; i < 4; ++i) {
                z6c[tt][0][i] = z6n[tt][0][i];
                z6c[tt][1][i] = z6n[tt][1][i];
                ac[tt][i] = aN[tt][i];
            }
        WGSYNC();
    }

    // ---- epilogue ----
#pragma unroll
    for (int tt = 0; tt < 2; ++tt)
#pragma unroll
        for (int j = 0; j < 2; ++j)
#pragma unroll
            for (int i = 0; i < 4; ++i) {
                const float v = sigm(kold[tt][j][i]);
                const int off = (b0[tt] + quad * 4 + i) * EDIM + col_[j];
                if (BF) ((u16*)outv)[off] = f2bf(v);
                else    ((float*)outv)[off] = v;
            }
}

// ---------------------------------------------------------------------------
extern "C" void kernel_launch(void* const* d_in, const int* in_sizes, int n_in,
                              void* d_out, int out_size, void* d_ws, size_t ws_size,
                              hipStream_t stream) {
    static const int exp_sizes[27] = {
        128000, 128000, 128000, 128000, 128000,
        128000, 128000, 128000, 128000,
        16384000,
        128128, 13056, 13056, 256, 128,
        65536, 128, 16384, 128, 16384, 128,
        32768, 128, 32768, 128, 65536, 128
    };
    bool sizes_ok = (n_in == 27) && (out_size == 32768);
    if (sizes_ok)
        for (int i = 0; i < 27; ++i)
            if (in_sizes[i] != exp_sizes[i]) { sizes_ok = false; break; }
    if (!sizes_ok) {
        dimkt_sentinel<<<dim3(128), dim3(256), 0, stream>>>((u16*)d_out, (u16)0xC080); // -4.0
        return;
    }
    const size_t WS_NEED = 724480;
    if (ws_size < WS_NEED) {
        dimkt_sentinel<<<dim3(128), dim3(256), 0, stream>>>((u16*)d_out, (u16)0x4110); // 9.0
        return;
    }

    const int* c   = (const int*)d_in[1];
    const int* sd  = (const int*)d_in[2];
    const int* qd  = (const int*)d_in[3];
    const int* a   = (const int*)d_in[4];
    const void* q_emb = d_in[9];
    const void* c_tab = d_in[10];
    const void* sd_tab = d_in[11];
    const void* qd_tab = d_in[12];
    const void* a_tab = d_in[13];
    const void* knowledge = d_in[14];
    const void* W1 = d_in[15]; const void* b1 = d_in[16];
    const void* W2 = d_in[17]; const void* b2 = d_in[18];
    const void* W3 = d_in[19]; const void* b3 = d_in[20];
    const void* W4 = d_in[21]; const void* b4 = d_in[22];
    const void* W5 = d_in[23]; const void* b5 = d_in[24];
    const void* W6 = d_in[25]; const void* b6 = d_in[26];

    // ws: bf16 tables + fp32 c4t/c5t = 363,264 B (< 724,480 verified floor)
    u16* cW1pu = (u16*)d_ws;            // 128128
    u16* sdQu  = cW1pu + 128128;        // 26112
    u16* qdQu  = sdQu + 26112;          // 26112
    u16* aW6pu = qdQu + 26112;          // 256
    float* c4t = (float*)(aW6pu + 256); // 256 (byte off 361216, 4-aligned)
    float* c5t = c4t + 256;             // 256

    dimkt_tabs<<<dim3(1415), dim3(128), 0, stream>>>(
        q_emb, c_tab, sd_tab, qd_tab, a_tab, W1, W4, W5, W6, b4, b5, b6,
        cW1pu, sdQu, qdQu, aW6pu, c4t, c5t);

    (void)hipFuncSetAttribute((const void*)&dimkt_scan<true>,
                              hipFuncAttributeMaxDynamicSharedMemorySize, LDS_BYTES);
    (void)hipFuncSetAttribute((const void*)&dimkt_scan<false>,
                              hipFuncAttributeMaxDynamicSharedMemorySize, LDS_BYTES);

    dimkt_scan<true><<<dim3(8), dim3(256), LDS_BYTES, stream>>>(
        q_emb, c, sd, qd, a, W1, b1, W2, b2, W3, b3, W4, W5, W6, knowledge,
        cW1pu, sdQu, qdQu, aW6pu, c4t, c5t, d_out);
    dimkt_scan<false><<<dim3(8), dim3(256), LDS_BYTES, stream>>>(
        q_emb, c, sd, qd, a, W1, b1, W2, b2, W3, b3, W4, W5, W6, knowledge,
        cW1pu, sdQu, qdQu, aW6pu, c4t, c5t, d_out);
}